// Round 1
// 751.334 us; speedup vs baseline: 1.0089x; 1.0089x over previous
//
#include <hip/hip_runtime.h>

typedef unsigned short u16;
typedef __bf16 bf16x8 __attribute__((ext_vector_type(8)));
typedef float floatx4 __attribute__((ext_vector_type(4)));

#define NE 800000
#define NN 50000
#define CHUNKS 32
#define CHUNK (NE / CHUNKS)   // 25000
#define WIN 25000             // histogram window per segment (2 windows per array)

__device__ __forceinline__ float b2f(unsigned u) { return __uint_as_float(u << 16); }
__device__ __forceinline__ u16 f2b(float f) {
  unsigned x = __float_as_uint(f);
  x += 0x7fffu + ((x >> 16) & 1u);
  return (u16)(x >> 16);
}

// ---------------- histogram degrees (LDS, atomic-free in HBM) ----------------
// segment g in [0,12): array a=g>>1, window r=g&1 covering idx in [r*WIN,(r+1)*WIN)
// arrays: 0=dstF 1=dstRB 2=dstR 3=srcF 4=srcR 5=srcRB  (matches DI layout below)
__global__ __launch_bounds__(256) void k_hist(
    const int* __restrict__ dF, const int* __restrict__ dRB, const int* __restrict__ dR,
    const int* __restrict__ sF, const int* __restrict__ sR, const int* __restrict__ sRB,
    u16* __restrict__ partial) {
  __shared__ unsigned h[WIN / 2];          // packed u16 pairs, 50 KB
  int c = blockIdx.x, g = blockIdx.y, t = threadIdx.x;
  int a = g >> 1, lo = (g & 1) * WIN;
  for (int i = t; i < WIN / 2; i += 256) h[i] = 0;
  __syncthreads();
  const int* idx = (a == 0) ? dF : (a == 1) ? dRB : (a == 2) ? dR
                 : (a == 3) ? sF : (a == 4) ? sR : sRB;
  int st = c * CHUNK, en = st + CHUNK;
  for (int e = st + t; e < en; e += 256) {
    unsigned u = (unsigned)(idx[e] - lo);
    if (u < (unsigned)WIN) atomicAdd(&h[u >> 1], 1u << ((u & 1) * 16));
  }
  __syncthreads();
  unsigned* po = (unsigned*)(partial + ((size_t)g * CHUNKS + c) * WIN);
  for (int i = t; i < WIN / 2; i += 256) po[i] = h[i];
}

// partials -> DI counts; byproduct: exclusive per-chunk cumsum for relations (g<6)
__global__ __launch_bounds__(256) void k_hreduce(const u16* __restrict__ partial,
                                                 u16* __restrict__ chunkcum,
                                                 int* __restrict__ DI) {
  int i = blockIdx.x * 256 + threadIdx.x;
  int g = blockIdx.y;
  if (i >= WIN) return;
  const u16* p = partial + (size_t)g * CHUNKS * WIN + i;
  u16* cc = chunkcum + (size_t)g * CHUNKS * WIN + i;   // only meaningful for g<6
  int run = 0;
#pragma unroll
  for (int c = 0; c < CHUNKS; ++c) {
    if (g < 6) cc[(size_t)c * WIN] = (u16)run;
    run += p[(size_t)c * WIN];
  }
  int a = g >> 1, r = g & 1;
  DI[a * NN + r * WIN + i] = run;
}

// parallel exclusive scan over 150000 counts -> offs[0..150000]
__global__ __launch_bounds__(1024) void k_scan1(const int* __restrict__ cnt,
                                                int* __restrict__ offs,
                                                int* __restrict__ partials) {
  __shared__ int tmp[1024];
  int t = threadIdx.x, i = blockIdx.x * 1024 + t;
  int c = (i < 150000) ? cnt[i] : 0;
  tmp[t] = c; __syncthreads();
  for (int off = 1; off < 1024; off <<= 1) {
    int v = (t >= off) ? tmp[t - off] : 0;
    __syncthreads();
    tmp[t] += v;
    __syncthreads();
  }
  if (i <= 150000) offs[i] = tmp[t] - c;
  if (t == 1023) partials[blockIdx.x] = tmp[1023];
}

__global__ __launch_bounds__(256) void k_scan2(int* __restrict__ partials) {
  __shared__ int tmp[256];
  int t = threadIdx.x;
  int c = (t < 147) ? partials[t] : 0;
  tmp[t] = c; __syncthreads();
  for (int off = 1; off < 256; off <<= 1) {
    int v = (t >= off) ? tmp[t - off] : 0;
    __syncthreads();
    tmp[t] += v;
    __syncthreads();
  }
  if (t < 147) partials[t] = tmp[t] - c;
}

__global__ __launch_bounds__(1024) void k_scan3(int* __restrict__ offs,
                                                const int* __restrict__ partials) {
  int i = blockIdx.x * 1024 + threadIdx.x;
  if (i <= 150000) offs[i] += partials[blockIdx.x];
}

__global__ void k_rsq(int* __restrict__ DI, int n) {
  int i = blockIdx.x * 256 + threadIdx.x;
  if (i < n) {
    float v = (float)DI[i];
    ((float*)DI)[i] = rsqrtf(fmaxf(v, 1.f));
  }
}

// CSR scatter, atomic-free: slot = offs[dst] + chunkcum[dst] + LDS-rank
__global__ __launch_bounds__(256) void k_scatlds(
    const int* __restrict__ sF, const int* __restrict__ dF,
    const int* __restrict__ sRB, const int* __restrict__ dRB,
    const int* __restrict__ sR, const int* __restrict__ dR,
    const int* __restrict__ offs, const u16* __restrict__ chunkcum,
    int* __restrict__ csr) {
  __shared__ unsigned h[WIN / 2];          // rank counters, 50 KB
  int c = blockIdx.x, g = blockIdx.y, t = threadIdx.x;
  int a = g >> 1, lo = (g & 1) * WIN;
  for (int i = t; i < WIN / 2; i += 256) h[i] = 0;
  __syncthreads();
  const int* s = (a == 0) ? sF : (a == 1) ? sRB : sR;
  const int* d = (a == 0) ? dF : (a == 1) ? dRB : dR;
  int base = a * NN;
  const u16* cc = chunkcum + ((size_t)g * CHUNKS + c) * WIN;
  int st = c * CHUNK, en = st + CHUNK;
  for (int e = st + t; e < en; e += 256) {
    int dd = d[e];
    unsigned u = (unsigned)(dd - lo);
    if (u < (unsigned)WIN) {
      unsigned sh = (u & 1) * 16;
      unsigned old = atomicAdd(&h[u >> 1], 1u << sh);
      int r = (int)((old >> sh) & 0xffffu);
      csr[offs[base + dd] + (int)cc[u] + r] = s[e];
    }
  }
}

// 6 weight transposes fused: dst[n*256+k] = f2b(src[k*N+n]), K=256 rows
__global__ void k_tpose6(const float* __restrict__ W1f, const float* __restrict__ W1rt,
                         const float* __restrict__ W1rb, const float* __restrict__ W2f,
                         const float* __restrict__ W2rt, const float* __restrict__ W2rb,
                         u16* __restrict__ Bt1u, u16* __restrict__ Bt1i,
                         u16* __restrict__ Bt2u, u16* __restrict__ Bt2i) {
  int a = blockIdx.y;
  const float* src; u16* dst; int N;
  switch (a) {
    case 0: src = W1f;  dst = Bt1u;         N = 256; break;
    case 1: src = W1rt; dst = Bt1u + 65536; N = 256; break;
    case 2: src = W1rb; dst = Bt1i;         N = 256; break;
    case 3: src = W2f;  dst = Bt2u;         N = 128; break;
    case 4: src = W2rt; dst = Bt2u + 32768; N = 128; break;
    default: src = W2rb; dst = Bt2i;        N = 128; break;
  }
  int i = blockIdx.x * 256 + threadIdx.x;
  if (i < 256 * N) {
    int n = i >> 8, k = i & 255;
    dst[i] = f2b(src[(size_t)k * N + n]);
  }
}

// ---------------- GEMM: C[M,Ntot] = A[M,256] @ Bt[Ntot,256]^T, epilogue row-scale ----------------
template <bool AF32>
__global__ __launch_bounds__(256) void k_gemm(
    const void* __restrict__ A, const u16* __restrict__ Bt, u16* __restrict__ C,
    int M, int Ntot, const float* __restrict__ rs0, const float* __restrict__ rs1, int splitN) {
  __shared__ alignas(16) u16 As[128 * 64];
  __shared__ alignas(16) u16 Bs[128 * 64];
  const int tid = threadIdx.x;
  const int mBase = blockIdx.x * 128;
  const int nBase = blockIdx.y * 128;
  const int w = tid >> 6, lane = tid & 63;
  const int wm = w & 1, wn = w >> 1;
  const int lr = lane & 15, quad = lane >> 4;
  floatx4 acc[4][4] = {};
  for (int kb = 0; kb < 256; kb += 64) {
    uint4 va[4], vb[4];
#pragma unroll
    for (int c = 0; c < 4; ++c) {
      int idx = c * 256 + tid;
      int row = idx >> 3;
      int col8 = (idx & 7) * 8;
      int gr = mBase + row; if (gr > M - 1) gr = M - 1;
      if constexpr (AF32) {
        const float* ap = (const float*)A + (size_t)gr * 256 + kb + col8;
        float4 f0 = *(const float4*)ap;
        float4 f1 = *(const float4*)(ap + 4);
        va[c] = make_uint4(
            (unsigned)f2b(f0.x) | ((unsigned)f2b(f0.y) << 16),
            (unsigned)f2b(f0.z) | ((unsigned)f2b(f0.w) << 16),
            (unsigned)f2b(f1.x) | ((unsigned)f2b(f1.y) << 16),
            (unsigned)f2b(f1.z) | ((unsigned)f2b(f1.w) << 16));
      } else {
        va[c] = *(const uint4*)((const u16*)A + (size_t)gr * 256 + kb + col8);
      }
      vb[c] = *(const uint4*)(Bt + (size_t)(nBase + row) * 256 + kb + col8);
    }
#pragma unroll
    for (int c = 0; c < 4; ++c) {
      int idx = c * 256 + tid;
      *(uint4*)(&As[idx * 8]) = va[c];
      *(uint4*)(&Bs[idx * 8]) = vb[c];
    }
    __syncthreads();
#pragma unroll
    for (int ks = 0; ks < 2; ++ks) {
      bf16x8 fa[4], fb[4];
#pragma unroll
      for (int m = 0; m < 4; ++m)
        fa[m] = *(const bf16x8*)(&As[(wm * 64 + m * 16 + lr) * 64 + ks * 32 + quad * 8]);
#pragma unroll
      for (int n = 0; n < 4; ++n)
        fb[n] = *(const bf16x8*)(&Bs[(wn * 64 + n * 16 + lr) * 64 + ks * 32 + quad * 8]);
#pragma unroll
      for (int m = 0; m < 4; ++m)
#pragma unroll
        for (int n = 0; n < 4; ++n)
          acc[m][n] = __builtin_amdgcn_mfma_f32_16x16x32_bf16(fa[m], fb[n], acc[m][n], 0, 0, 0);
    }
    __syncthreads();
  }
#pragma unroll
  for (int n = 0; n < 4; ++n) {
    int cg = nBase + wn * 64 + n * 16 + lr;
    const float* rs = (cg < splitN) ? rs0 : rs1;
#pragma unroll
    for (int m = 0; m < 4; ++m) {
      int rb_ = mBase + wm * 64 + m * 16 + quad * 4;
#pragma unroll
      for (int r = 0; r < 4; ++r) {
        int rg = rb_ + r;
        if (rg < M) C[(size_t)rg * Ntot + cg] = f2b(acc[m][n][r] * rs[rg]);
      }
    }
  }
}

// ---------------- SpMM (CSR by dst), fp32 accumulate ----------------
// MLP-deep gather: batch loads into temporaries BEFORE accumulating so the
// compiler issues 8 independent global_load_dwordx2 under one waitcnt window.
// Theory: old unroll-x2 had only 2 rows in flight/wave -> BW = inflight/latency
// capped at ~3.8 TB/s HBM-side (latency ~900cy). 8 in flight -> ~2x.

__device__ __forceinline__ int clampi(int s) {
  return (s < 0) ? 0 : (s > NN - 1 ? NN - 1 : s);
}

template <int VEC>
__device__ __forceinline__ uint2 ldrow(const u16* __restrict__ p) {
  uint2 r;
  if constexpr (VEC == 4) {
    r = *(const uint2*)p;
  } else {
    r.x = *(const unsigned*)p;
    r.y = 0u;
  }
  return r;
}

template <int VEC>
__device__ __forceinline__ void accum(float* acc, uint2 v) {
  acc[0] += b2f(v.x & 0xffffu);
  acc[1] += b2f(v.x >> 16);
  if constexpr (VEC == 4) {
    acc[2] += b2f(v.y & 0xffffu);
    acc[3] += b2f(v.y >> 16);
  }
}

// N-deep single-relation batch: N loads in flight, then N accumulates.
template <int VEC, int N>
__device__ __forceinline__ void batch1(float* acc0, float* acc1,
                                       const u16* __restrict__ base, int stride,
                                       const int* __restrict__ csr, int e, int lane) {
  int idx[N];
  uint2 v[N];
#pragma unroll
  for (int k = 0; k < N; ++k) idx[k] = clampi(csr[e + k]);
#pragma unroll
  for (int k = 0; k < N; ++k)
    v[k] = ldrow<VEC>(base + (size_t)idx[k] * stride + lane * VEC);
#pragma unroll
  for (int k = 0; k < N; ++k) accum<VEC>((k & 1) ? acc1 : acc0, v[k]);
}

// fused two-relation batch: 4+4 loads in flight, then 8 accumulates.
template <int VEC>
__device__ __forceinline__ void batch2(float* aA0, float* aA1, float* aB0, float* aB1,
                                       const u16* __restrict__ bA, int sA,
                                       const u16* __restrict__ bB, int sB,
                                       const int* __restrict__ csr, int eA, int eB,
                                       int lane) {
  int ia[4], ib[4];
  uint2 va[4], vb[4];
#pragma unroll
  for (int k = 0; k < 4; ++k) ia[k] = clampi(csr[eA + k]);
#pragma unroll
  for (int k = 0; k < 4; ++k) ib[k] = clampi(csr[eB + k]);
#pragma unroll
  for (int k = 0; k < 4; ++k)
    va[k] = ldrow<VEC>(bA + (size_t)ia[k] * sA + lane * VEC);
#pragma unroll
  for (int k = 0; k < 4; ++k)
    vb[k] = ldrow<VEC>(bB + (size_t)ib[k] * sB + lane * VEC);
#pragma unroll
  for (int k = 0; k < 4; ++k) accum<VEC>((k & 1) ? aA1 : aA0, va[k]);
#pragma unroll
  for (int k = 0; k < 4; ++k) accum<VEC>((k & 1) ? aB1 : aB0, vb[k]);
}

template <int VEC, bool RELU, bool OUT32>
__global__ __launch_bounds__(64) void k_spmm2(
    const u16* __restrict__ fA, int sA, int oA,
    const u16* __restrict__ fB, int sB, int oB,
    const int* __restrict__ csr, const int* __restrict__ offs, int baseA, int baseB,
    const float* __restrict__ rsA, const float* __restrict__ rsB,
    const float* __restrict__ bA, const float* __restrict__ bB,
    void* __restrict__ outv, size_t outBase, int sOut) {
  int d = blockIdx.x, lane = threadIdx.x;
  float a0[VEC] = {}, a1[VEC] = {}, b0[VEC] = {}, b1[VEC] = {};
  int eA = offs[baseA + d], enA = offs[baseA + d + 1];
  int eB = offs[baseB + d], enB = offs[baseB + d + 1];
  const u16* pA = fA + oA;
  const u16* pB = fB + oB;
  // fused phase: 8 rows in flight
  while (eA + 4 <= enA && eB + 4 <= enB) {
    batch2<VEC>(a0, a1, b0, b1, pA, sA, pB, sB, csr, eA, eB, lane);
    eA += 4; eB += 4;
  }
  // drain A
  for (; eA + 4 <= enA; eA += 4) batch1<VEC, 4>(a0, a1, pA, sA, csr, eA, lane);
  for (; eA < enA; ++eA)
    accum<VEC>(a0, ldrow<VEC>(pA + (size_t)clampi(csr[eA]) * sA + lane * VEC));
  // drain B
  for (; eB + 4 <= enB; eB += 4) batch1<VEC, 4>(b0, b1, pB, sB, csr, eB, lane);
  for (; eB < enB; ++eB)
    accum<VEC>(b0, ldrow<VEC>(pB + (size_t)clampi(csr[eB]) * sB + lane * VEC));

  float ra = rsA[d], rb = rsB[d];
  size_t o = outBase + (size_t)d * sOut + lane * VEC;
#pragma unroll
  for (int v = 0; v < VEC; ++v) {
    float x = 0.5f * ((a0[v] + a1[v]) * ra + bA[lane * VEC + v]
                      + (b0[v] + b1[v]) * rb + bB[lane * VEC + v]);
    if (RELU) x = fmaxf(x, 0.f);
    if (OUT32) ((float*)outv)[o + v] = x;
    else       ((u16*)outv)[o + v] = f2b(x);
  }
}

template <int VEC, bool RELU, bool OUT32>
__global__ __launch_bounds__(64) void k_spmm1(
    const u16* __restrict__ fA, int sA, int oA,
    const int* __restrict__ csr, const int* __restrict__ offs, int baseA,
    const float* __restrict__ rsA, const float* __restrict__ bA,
    void* __restrict__ outv, size_t outBase, int sOut) {
  int d = blockIdx.x, lane = threadIdx.x;
  float a0[VEC] = {}, a1[VEC] = {};
  int e = offs[baseA + d], en = offs[baseA + d + 1];
  const u16* pA = fA + oA;
  for (; e + 8 <= en; e += 8) batch1<VEC, 8>(a0, a1, pA, sA, csr, e, lane);
  for (; e + 4 <= en; e += 4) batch1<VEC, 4>(a0, a1, pA, sA, csr, e, lane);
  for (; e < en; ++e)
    accum<VEC>(a0, ldrow<VEC>(pA + (size_t)clampi(csr[e]) * sA + lane * VEC));
  float ra = rsA[d];
  size_t o = outBase + (size_t)d * sOut + lane * VEC;
#pragma unroll
  for (int v = 0; v < VEC; ++v) {
    float x = (a0[v] + a1[v]) * ra + bA[lane * VEC + v];
    if (RELU) x = fmaxf(x, 0.f);
    if (OUT32) ((float*)outv)[o + v] = x;
    else       ((u16*)outv)[o + v] = f2b(x);
  }
}

extern "C" void kernel_launch(void* const* d_in, const int* in_sizes, int n_in,
                              void* d_out, int out_size, void* d_ws, size_t ws_size,
                              hipStream_t stream) {
  (void)in_sizes; (void)n_in; (void)out_size;
  const float* x_user = (const float*)d_in[0];
  const float* x_item = (const float*)d_in[1];
  const float* W1f  = (const float*)d_in[2];  const float* b1f  = (const float*)d_in[3];
  const float* W1rt = (const float*)d_in[4];  const float* b1rt = (const float*)d_in[5];
  const float* W1rb = (const float*)d_in[6];  const float* b1rb = (const float*)d_in[7];
  const float* W2f  = (const float*)d_in[8];  const float* b2fo = (const float*)d_in[9];
  const float* W2rt = (const float*)d_in[10]; const float* b2rt = (const float*)d_in[11];
  const float* W2rb = (const float*)d_in[12]; const float* b2rb = (const float*)d_in[13];
  const int* srcF  = (const int*)d_in[14]; const int* dstF  = (const int*)d_in[15];
  const int* srcR  = (const int*)d_in[16]; const int* dstR  = (const int*)d_in[17];
  const int* srcRB = (const int*)d_in[18]; const int* dstRB = (const int*)d_in[19];

  // ---- workspace layout (bytes) ----
  // DI/R   : [0, 1200000)           300000 i32 -> f32 in place
  // offs   : [1800064, 2400068)     150001 i32
  // csr    : [2400128, 12000128)    2400000 i32  (first 588 B double as scan partials)
  // Bt1u/Bt1i/Bt2u/Bt2i bf16        [12000128, 12589952)
  // featA  : [12589952, 63789952)   [50000,512] bf16
  //          scratch (pre-GEMM): partial u16 12*32*25000 @featA+0 (19.2MB),
  //                              chunkcum u16 6*32*25000 @featA+19.2MB (9.6MB)
  // featB  : [63789952, 89389952)   [50000,256]
  // h_u    : [89389952, 114989952)  [50000,256]
  if (ws_size < 114989952u) return;

  char* ws = (char*)d_ws;
  int*   DI     = (int*)ws;
  float* R      = (float*)ws;
  int*   offs   = (int*)(ws + 1800064);
  int*   csr    = (int*)(ws + 2400128);
  int*   partials = csr;                    // scan scratch, free until k_scatlds
  u16*   Bt1u   = (u16*)(ws + 12000128);
  u16*   Bt1i   = (u16*)(ws + 12262272);
  u16*   Bt2u   = (u16*)(ws + 12393344);
  u16*   Bt2i   = (u16*)(ws + 12524416);
  u16*   featA  = (u16*)(ws + 12589952);
  u16*   featB  = (u16*)(ws + 63789952);
  u16*   h_u    = (u16*)(ws + 89389952);
  u16*   h_i    = featB;
  u16*   feat2rb = featA + (size_t)50000 * 256;
  u16*   hpart  = featA;                    // 12*32*25000 u16, dead before GEMM1
  u16*   chunkcum = featA + (size_t)12 * CHUNKS * WIN;  // 6*32*25000 u16

  k_hist<<<dim3(CHUNKS, 12), 256, 0, stream>>>(dstF, dstRB, dstR, srcF, srcR, srcRB, hpart);
  k_hreduce<<<dim3(98, 12), 256, 0, stream>>>(hpart, chunkcum, DI);
  k_scan1<<<147, 1024, 0, stream>>>(DI, offs, partials);
  k_scan2<<<1, 256, 0, stream>>>(partials);
  k_scan3<<<147, 1024, 0, stream>>>(offs, partials);
  k_rsq<<<(300000 + 255) / 256, 256, 0, stream>>>(DI, 300000);
  k_scatlds<<<dim3(CHUNKS, 6), 256, 0, stream>>>(srcF, dstF, srcRB, dstRB, srcR, dstR,
                                                 offs, chunkcum, csr);
  k_tpose6<<<dim3(256, 6), 256, 0, stream>>>(W1f, W1rt, W1rb, W2f, W2rt, W2rb,
                                             Bt1u, Bt1i, Bt2u, Bt2i);

  // layer 1 GEMMs (rsqrt(out_deg) row scale commutes with @W; applied in epilogue)
  k_gemm<true><<<dim3(391, 4), 256, 0, stream>>>(x_user, Bt1u, featA, 50000, 512,
                                                 R + 150000, R + 200000, 256);
  k_gemm<true><<<dim3(391, 2), 256, 0, stream>>>(x_item, Bt1i, featB, 50000, 256,
                                                 R + 250000, R + 250000, 256);
  // layer 1 aggregation (bf16 stores into ws)
  k_spmm2<4, true, false><<<50000, 64, 0, stream>>>(featA, 512, 0, featB, 256, 0,
                                                    csr, offs, 0, 50000,
                                                    R, R + 50000, b1f, b1rb, h_u, 0, 256);
  k_spmm1<4, true, false><<<50000, 64, 0, stream>>>(featA, 512, 256, csr, offs, 100000,
                                                    R + 100000, b1rt, h_i, 0, 256);
  // layer 2 GEMMs (A = bf16 ws buffers)
  k_gemm<false><<<dim3(391, 2), 256, 0, stream>>>(h_u, Bt2u, featA, 50000, 256,
                                                  R + 150000, R + 200000, 128);
  k_gemm<false><<<dim3(391, 1), 256, 0, stream>>>(h_i, Bt2i, feat2rb, 50000, 128,
                                                  R + 250000, R + 250000, 128);
  // layer 2 aggregation -> d_out (fp32)
  k_spmm2<2, false, true><<<50000, 64, 0, stream>>>(featA, 256, 0, feat2rb, 128, 0,
                                                    csr, offs, 0, 50000,
                                                    R, R + 50000, b2fo, b2rb, d_out, 0, 128);
  k_spmm1<2, false, true><<<50000, 64, 0, stream>>>(featA, 256, 128, csr, offs, 100000,
                                                    R + 100000, b2rt, d_out, (size_t)50000 * 128, 128);
}